// Round 1
// baseline (622.707 us; speedup 1.0000x reference)
//
#include <hip/hip_runtime.h>

// GCN 3-layer forward on MI355X.
// Strategy: per-call CSR build (by dst), then per-layer:
//   agg[v] = sum_{u->v} norm_src[u] * x[u]   (wave-per-node, register accum)
//   h = relu(norm_dst[v] * agg @ W + b)      (LDS-tiled fp32 matmul)
// Layer 3 swaps order: y = (norm_src*h2)@W3 first (128->40), then 40-dim agg.

__global__ void degree_kernel(const int* __restrict__ ei, int E,
                              int* __restrict__ deg_out, int* __restrict__ deg_in) {
    int e = blockIdx.x * blockDim.x + threadIdx.x;
    if (e < E) {
        atomicAdd(&deg_out[ei[e]], 1);
        atomicAdd(&deg_in[ei[E + e]], 1);
    }
}

__global__ void norm_kernel(const int* __restrict__ deg_out, const int* __restrict__ deg_in,
                            float* __restrict__ norm_src, float* __restrict__ norm_dst, int n) {
    int i = blockIdx.x * blockDim.x + threadIdx.x;
    if (i < n) {
        int dо = deg_out[i] > 0 ? deg_out[i] : 1;
        int di = deg_in[i] > 0 ? deg_in[i] : 1;
        norm_src[i] = rsqrtf((float)dо);
        norm_dst[i] = rsqrtf((float)di);
    }
}

// Single-block exclusive scan of deg_in -> row_ptr (and cursor copy).
__global__ void scan_kernel(const int* __restrict__ deg_in, int n,
                            int* __restrict__ row_ptr, int* __restrict__ cursor) {
    __shared__ int partial[1024];
    int t = threadIdx.x;
    int chunk = (n + 1023) >> 10;
    int base = t * chunk;
    int s = 0;
    for (int i = 0; i < chunk; ++i) {
        int idx = base + i;
        if (idx < n) s += deg_in[idx];
    }
    partial[t] = s;
    __syncthreads();
    for (int off = 1; off < 1024; off <<= 1) {
        int v = 0;
        if (t >= off) v = partial[t - off];
        __syncthreads();
        partial[t] += v;
        __syncthreads();
    }
    int run = (t == 0) ? 0 : partial[t - 1];
    for (int i = 0; i < chunk; ++i) {
        int idx = base + i;
        if (idx < n) {
            row_ptr[idx] = run;
            cursor[idx]  = run;
            run += deg_in[idx];
        }
    }
    if (t == 1023) row_ptr[n] = partial[1023];
}

__global__ void fill_kernel(const int* __restrict__ ei, int E,
                            int* __restrict__ cursor, int* __restrict__ col) {
    int e = blockIdx.x * blockDim.x + threadIdx.x;
    if (e < E) {
        int s = ei[e];
        int d = ei[E + e];
        int slot = atomicAdd(&cursor[d], 1);
        col[slot] = s;
    }
}

// One wave per node: acc[v][:] = sum_{u in in(v)} norm_src[u] * x[u][:], D=128.
// Lane l holds dims 2l, 2l+1 (float2). Edge ids batched 64/wave via shfl.
__global__ __launch_bounds__(256) void agg128_kernel(const float* __restrict__ x,
        const int* __restrict__ row_ptr, const int* __restrict__ col,
        const float* __restrict__ norm_src, float* __restrict__ out, int n) {
    int wid  = (blockIdx.x * blockDim.x + threadIdx.x) >> 6;
    int lane = threadIdx.x & 63;
    if (wid >= n) return;
    int start = row_ptr[wid], end = row_ptr[wid + 1];
    float a0 = 0.f, a1 = 0.f;
    for (int b = start; b < end; b += 64) {
        int m = end - b; if (m > 64) m = 64;
        int u = 0; float s = 0.f;
        if (lane < m) { u = col[b + lane]; s = norm_src[u]; }
        for (int j = 0; j < m; ++j) {
            int   uu = __shfl(u, j);
            float ss = __shfl(s, j);
            const float2 xv = *reinterpret_cast<const float2*>(&x[(size_t)uu * 128 + 2 * lane]);
            a0 = fmaf(ss, xv.x, a0);
            a1 = fmaf(ss, xv.y, a1);
        }
    }
    float2 o; o.x = a0; o.y = a1;
    *reinterpret_cast<float2*>(&out[(size_t)wid * 128 + 2 * lane]) = o;
}

// out[r][:] = relu( rowscale[r] * xin[r][:] @ W + b ), W is 128x128 row-major.
// 64 rows/block; W (64KB) + X tile (32KB) in LDS; wave w -> rows w*16..+15,
// lane -> cols (lane, lane+64).
__global__ __launch_bounds__(256) void mm128_kernel(const float* __restrict__ xin,
        const float* __restrict__ W, const float* __restrict__ bias,
        const float* __restrict__ rowscale, float* __restrict__ out, int n, int do_relu) {
    __shared__ float Wl[128 * 128];
    __shared__ float Xl[64][128];
    int t = threadIdx.x;
    for (int i = t; i < 128 * 32; i += 256)
        reinterpret_cast<float4*>(Wl)[i] = reinterpret_cast<const float4*>(W)[i];
    int row0 = blockIdx.x * 64;
    for (int i = t; i < 64 * 32; i += 256) {
        int r = i >> 5, k4 = i & 31;
        int gr = row0 + r;
        float4 xv;
        if (gr < n) {
            xv = reinterpret_cast<const float4*>(xin)[(size_t)gr * 32 + k4];
            float sc = rowscale[gr];
            xv.x *= sc; xv.y *= sc; xv.z *= sc; xv.w *= sc;
        } else { xv = make_float4(0.f, 0.f, 0.f, 0.f); }
        reinterpret_cast<float4*>(&Xl[r][0])[k4] = xv;
    }
    __syncthreads();
    int wv = t >> 6, lane = t & 63;
    int c0 = lane, c1 = lane + 64;
    float acc0[16], acc1[16];
    #pragma unroll
    for (int r = 0; r < 16; ++r) { acc0[r] = 0.f; acc1[r] = 0.f; }
    int rbase = wv * 16;
    for (int k = 0; k < 128; k += 4) {
        float w00 = Wl[(k + 0) * 128 + c0], w10 = Wl[(k + 0) * 128 + c1];
        float w01 = Wl[(k + 1) * 128 + c0], w11 = Wl[(k + 1) * 128 + c1];
        float w02 = Wl[(k + 2) * 128 + c0], w12 = Wl[(k + 2) * 128 + c1];
        float w03 = Wl[(k + 3) * 128 + c0], w13 = Wl[(k + 3) * 128 + c1];
        #pragma unroll
        for (int r = 0; r < 16; ++r) {
            float4 xv = *reinterpret_cast<const float4*>(&Xl[rbase + r][k]);
            acc0[r] = fmaf(xv.x, w00, acc0[r]);
            acc1[r] = fmaf(xv.x, w10, acc1[r]);
            acc0[r] = fmaf(xv.y, w01, acc0[r]);
            acc1[r] = fmaf(xv.y, w11, acc1[r]);
            acc0[r] = fmaf(xv.z, w02, acc0[r]);
            acc1[r] = fmaf(xv.z, w12, acc1[r]);
            acc0[r] = fmaf(xv.w, w03, acc0[r]);
            acc1[r] = fmaf(xv.w, w13, acc1[r]);
        }
    }
    float b0 = bias[c0], b1 = bias[c1];
    #pragma unroll
    for (int r = 0; r < 16; ++r) {
        int gr = row0 + rbase + r;
        if (gr < n) {
            float v0 = acc0[r] + b0, v1 = acc1[r] + b1;
            if (do_relu) { v0 = fmaxf(v0, 0.f); v1 = fmaxf(v1, 0.f); }
            out[(size_t)gr * 128 + c0] = v0;
            out[(size_t)gr * 128 + c1] = v1;
        }
    }
}

// y[r][c] = rowscale[r] * xin[r][:] @ W3[:,c], c < 40 (padded to 64 lanes). No bias/relu.
__global__ __launch_bounds__(256) void mm40_kernel(const float* __restrict__ xin,
        const float* __restrict__ W, const float* __restrict__ rowscale,
        float* __restrict__ out, int n) {
    __shared__ float Wl[128 * 64];
    __shared__ float Xl[64][128];
    int t = threadIdx.x;
    for (int i = t; i < 128 * 64; i += 256) {
        int k = i >> 6, c = i & 63;
        Wl[i] = (c < 40) ? W[k * 40 + c] : 0.f;
    }
    int row0 = blockIdx.x * 64;
    for (int i = t; i < 64 * 32; i += 256) {
        int r = i >> 5, k4 = i & 31;
        int gr = row0 + r;
        float4 xv;
        if (gr < n) {
            xv = reinterpret_cast<const float4*>(xin)[(size_t)gr * 32 + k4];
            float sc = rowscale[gr];
            xv.x *= sc; xv.y *= sc; xv.z *= sc; xv.w *= sc;
        } else { xv = make_float4(0.f, 0.f, 0.f, 0.f); }
        reinterpret_cast<float4*>(&Xl[r][0])[k4] = xv;
    }
    __syncthreads();
    int wv = t >> 6, lane = t & 63;
    float acc[16];
    #pragma unroll
    for (int r = 0; r < 16; ++r) acc[r] = 0.f;
    int rbase = wv * 16;
    for (int k = 0; k < 128; k += 2) {
        float w0 = Wl[(k + 0) * 64 + lane];
        float w1 = Wl[(k + 1) * 64 + lane];
        #pragma unroll
        for (int r = 0; r < 16; ++r) {
            float2 xv = *reinterpret_cast<const float2*>(&Xl[rbase + r][k]);
            acc[r] = fmaf(xv.x, w0, acc[r]);
            acc[r] = fmaf(xv.y, w1, acc[r]);
        }
    }
    if (lane < 40) {
        #pragma unroll
        for (int r = 0; r < 16; ++r) {
            int gr = row0 + rbase + r;
            if (gr < n) out[(size_t)gr * 40 + lane] = acc[r];
        }
    }
}

// out[v][c] = norm_dst[v] * sum_{u->v} y[u][c] + b3[c], c < 40. One wave/node.
__global__ __launch_bounds__(256) void agg40_kernel(const float* __restrict__ y,
        const int* __restrict__ row_ptr, const int* __restrict__ col,
        const float* __restrict__ norm_dst, const float* __restrict__ b3,
        float* __restrict__ out, int n) {
    int wid  = (blockIdx.x * blockDim.x + threadIdx.x) >> 6;
    int lane = threadIdx.x & 63;
    if (wid >= n) return;
    int start = row_ptr[wid], end = row_ptr[wid + 1];
    float acc = 0.f;
    for (int b = start; b < end; b += 64) {
        int m = end - b; if (m > 64) m = 64;
        int u = 0;
        if (lane < m) u = col[b + lane];
        for (int j = 0; j < m; ++j) {
            int uu = __shfl(u, j);
            if (lane < 40) acc += y[(size_t)uu * 40 + lane];
        }
    }
    if (lane < 40) out[(size_t)wid * 40 + lane] = norm_dst[wid] * acc + b3[lane];
}

extern "C" void kernel_launch(void* const* d_in, const int* in_sizes, int n_in,
                              void* d_out, int out_size, void* d_ws, size_t ws_size,
                              hipStream_t stream) {
    const float* features = (const float*)d_in[0];
    const int*   ei       = (const int*)d_in[1];
    const float* W1 = (const float*)d_in[2];
    const float* b1 = (const float*)d_in[3];
    const float* W2 = (const float*)d_in[4];
    const float* b2 = (const float*)d_in[5];
    const float* W3 = (const float*)d_in[6];
    const float* b3 = (const float*)d_in[7];

    const int n = in_sizes[0] / 128;
    const int E = in_sizes[1] / 2;

    char* w = (char*)d_ws;
    auto alloc = [&](size_t bytes) {
        char* p = w;
        w += (bytes + 255) & ~(size_t)255;
        return p;
    };
    int*   deg      = (int*)  alloc((size_t)2 * n * 4);  // deg_out | deg_in
    float* norm_src = (float*)alloc((size_t)n * 4);
    float* norm_dst = (float*)alloc((size_t)n * 4);
    int*   row_ptr  = (int*)  alloc((size_t)(n + 1) * 4);
    int*   cursor   = (int*)  alloc((size_t)n * 4);
    int*   col      = (int*)  alloc((size_t)E * 4);
    float* bufA     = (float*)alloc((size_t)n * 128 * 4);
    float* bufB     = (float*)alloc((size_t)n * 128 * 4);

    int* deg_out = deg;
    int* deg_in  = deg + n;

    hipMemsetAsync(deg, 0, (size_t)2 * n * 4, stream);

    int eb = (E + 255) / 256;
    int nb = (n + 255) / 256;
    degree_kernel<<<eb, 256, 0, stream>>>(ei, E, deg_out, deg_in);
    norm_kernel<<<nb, 256, 0, stream>>>(deg_out, deg_in, norm_src, norm_dst, n);
    scan_kernel<<<1, 1024, 0, stream>>>(deg_in, n, row_ptr, cursor);
    fill_kernel<<<eb, 256, 0, stream>>>(ei, E, cursor, col);

    int ab = (n + 3) / 4;    // 4 node-waves per 256-thread block
    int mb = (n + 63) / 64;  // 64 rows per matmul block

    agg128_kernel<<<ab, 256, 0, stream>>>(features, row_ptr, col, norm_src, bufA, n);
    mm128_kernel<<<mb, 256, 0, stream>>>(bufA, W1, b1, norm_dst, bufB, n, 1);
    agg128_kernel<<<ab, 256, 0, stream>>>(bufB, row_ptr, col, norm_src, bufA, n);
    mm128_kernel<<<mb, 256, 0, stream>>>(bufA, W2, b2, norm_dst, bufB, n, 1);
    mm40_kernel<<<mb, 256, 0, stream>>>(bufB, W3, norm_src, bufA, n);
    agg40_kernel<<<ab, 256, 0, stream>>>(bufA, row_ptr, col, norm_dst, b3, (float*)d_out, n);
}

// Round 2
// 530.196 us; speedup vs baseline: 1.1745x; 1.1745x over previous
//
#include <hip/hip_runtime.h>

// GCN 3-layer forward on MI355X.
// Per-call CSR build (by dst) with hierarchical scan, then per-layer:
//   agg[v] = sum_{u->v} norm_src[u] * x[u]   (wave-per-node, register accum)
//   h = relu(norm_dst[v] * agg @ W + b)      (LDS-tiled fp32 matmul)
// Layer 3 swaps order: y = (norm_src*h2)@W3 first (128->40), then 40-dim agg.

#define SCAN_CHUNK 4096  // elements per scan block (256 threads x 16)

__global__ void degree_kernel(const int* __restrict__ ei, int E,
                              int* __restrict__ deg_out, int* __restrict__ deg_in) {
    int e = blockIdx.x * blockDim.x + threadIdx.x;
    if (e < E) {
        atomicAdd(&deg_out[ei[e]], 1);
        atomicAdd(&deg_in[ei[E + e]], 1);
    }
}

// Phase 1: coalesced per-block sums of deg_in.
__global__ __launch_bounds__(256) void scan_blocksum(const int* __restrict__ deg_in, int n,
                                                     int* __restrict__ partials) {
    __shared__ int red[256];
    int t = threadIdx.x;
    int base = blockIdx.x * SCAN_CHUNK;
    int s = 0;
    for (int i = t; i < SCAN_CHUNK; i += 256) {
        int idx = base + i;
        if (idx < n) s += deg_in[idx];
    }
    red[t] = s;
    __syncthreads();
    for (int off = 128; off > 0; off >>= 1) {
        if (t < off) red[t] += red[t + off];
        __syncthreads();
    }
    if (t == 0) partials[blockIdx.x] = red[0];
}

// Phase 2: exclusive scan of partials (nparts <= 256) + write row_ptr[n].
__global__ __launch_bounds__(256) void scan_partials(int* __restrict__ partials, int nparts,
                                                     int* __restrict__ row_ptr, int n) {
    __shared__ int s[256];
    int t = threadIdx.x;
    s[t] = (t < nparts) ? partials[t] : 0;
    __syncthreads();
    for (int off = 1; off < 256; off <<= 1) {
        int v = (t >= off) ? s[t - off] : 0;
        __syncthreads();
        s[t] += v;
        __syncthreads();
    }
    int incl = s[t];
    int excl = incl - ((t < nparts) ? partials[t] : 0);
    if (t < nparts) partials[t] = excl;
    if (t == 255) row_ptr[n] = incl;  // total (tail of s is zero-padded)
}

// Phase 3: per-chunk exclusive scan + emit row_ptr/cursor + fused norm compute.
__global__ __launch_bounds__(256) void scan_emit(const int* __restrict__ deg_in,
                                                 const int* __restrict__ deg_out,
                                                 const int* __restrict__ partials, int n,
                                                 int* __restrict__ row_ptr, int* __restrict__ cursor,
                                                 float* __restrict__ norm_src,
                                                 float* __restrict__ norm_dst) {
    __shared__ int tsum[256];
    int t = threadIdx.x;
    int base = blockIdx.x * SCAN_CHUNK + t * 16;
    int local[16];
    int s = 0;
    #pragma unroll
    for (int i = 0; i < 16; ++i) {
        int idx = base + i;
        int v = (idx < n) ? deg_in[idx] : 0;
        local[i] = v;
        s += v;
    }
    tsum[t] = s;
    __syncthreads();
    for (int off = 1; off < 256; off <<= 1) {
        int v = (t >= off) ? tsum[t - off] : 0;
        __syncthreads();
        tsum[t] += v;
        __syncthreads();
    }
    int run = partials[blockIdx.x] + (t ? tsum[t - 1] : 0);
    #pragma unroll
    for (int i = 0; i < 16; ++i) {
        int idx = base + i;
        if (idx < n) {
            row_ptr[idx] = run;
            cursor[idx]  = run;
            run += local[i];
            int di = local[i] > 0 ? local[i] : 1;
            int dq = deg_out[idx] > 0 ? deg_out[idx] : 1;
            norm_dst[idx] = rsqrtf((float)di);
            norm_src[idx] = rsqrtf((float)dq);
        }
    }
}

__global__ void fill_kernel(const int* __restrict__ ei, int E,
                            int* __restrict__ cursor, int* __restrict__ col) {
    int e = blockIdx.x * blockDim.x + threadIdx.x;
    if (e < E) {
        int s = ei[e];
        int d = ei[E + e];
        int slot = atomicAdd(&cursor[d], 1);
        col[slot] = s;
    }
}

// One wave per node: acc[v][:] = sum_{u in in(v)} norm_src[u] * x[u][:], D=128.
// Lane l holds dims 2l, 2l+1 (float2). Edge ids batched 64/wave via shfl.
__global__ __launch_bounds__(256) void agg128_kernel(const float* __restrict__ x,
        const int* __restrict__ row_ptr, const int* __restrict__ col,
        const float* __restrict__ norm_src, float* __restrict__ out, int n) {
    int wid  = (blockIdx.x * blockDim.x + threadIdx.x) >> 6;
    int lane = threadIdx.x & 63;
    if (wid >= n) return;
    int start = row_ptr[wid], end = row_ptr[wid + 1];
    float a0 = 0.f, a1 = 0.f;
    for (int b = start; b < end; b += 64) {
        int m = end - b; if (m > 64) m = 64;
        int u = 0; float s = 0.f;
        if (lane < m) { u = col[b + lane]; s = norm_src[u]; }
        for (int j = 0; j < m; ++j) {
            int   uu = __shfl(u, j);
            float ss = __shfl(s, j);
            const float2 xv = *reinterpret_cast<const float2*>(&x[(size_t)uu * 128 + 2 * lane]);
            a0 = fmaf(ss, xv.x, a0);
            a1 = fmaf(ss, xv.y, a1);
        }
    }
    float2 o; o.x = a0; o.y = a1;
    *reinterpret_cast<float2*>(&out[(size_t)wid * 128 + 2 * lane]) = o;
}

// out[r][:] = relu( rowscale[r] * xin[r][:] @ W + b ), W is 128x128 row-major.
// 64 rows/block; W (64KB) + X tile (32KB) in LDS; wave w -> rows w*16..+15,
// lane -> cols (lane, lane+64).
__global__ __launch_bounds__(256) void mm128_kernel(const float* __restrict__ xin,
        const float* __restrict__ W, const float* __restrict__ bias,
        const float* __restrict__ rowscale, float* __restrict__ out, int n, int do_relu) {
    __shared__ float Wl[128 * 128];
    __shared__ float Xl[64][128];
    int t = threadIdx.x;
    for (int i = t; i < 128 * 32; i += 256)
        reinterpret_cast<float4*>(Wl)[i] = reinterpret_cast<const float4*>(W)[i];
    int row0 = blockIdx.x * 64;
    for (int i = t; i < 64 * 32; i += 256) {
        int r = i >> 5, k4 = i & 31;
        int gr = row0 + r;
        float4 xv;
        if (gr < n) {
            xv = reinterpret_cast<const float4*>(xin)[(size_t)gr * 32 + k4];
            float sc = rowscale[gr];
            xv.x *= sc; xv.y *= sc; xv.z *= sc; xv.w *= sc;
        } else { xv = make_float4(0.f, 0.f, 0.f, 0.f); }
        reinterpret_cast<float4*>(&Xl[r][0])[k4] = xv;
    }
    __syncthreads();
    int wv = t >> 6, lane = t & 63;
    int c0 = lane, c1 = lane + 64;
    float acc0[16], acc1[16];
    #pragma unroll
    for (int r = 0; r < 16; ++r) { acc0[r] = 0.f; acc1[r] = 0.f; }
    int rbase = wv * 16;
    for (int k = 0; k < 128; k += 4) {
        float w00 = Wl[(k + 0) * 128 + c0], w10 = Wl[(k + 0) * 128 + c1];
        float w01 = Wl[(k + 1) * 128 + c0], w11 = Wl[(k + 1) * 128 + c1];
        float w02 = Wl[(k + 2) * 128 + c0], w12 = Wl[(k + 2) * 128 + c1];
        float w03 = Wl[(k + 3) * 128 + c0], w13 = Wl[(k + 3) * 128 + c1];
        #pragma unroll
        for (int r = 0; r < 16; ++r) {
            float4 xv = *reinterpret_cast<const float4*>(&Xl[rbase + r][k]);
            acc0[r] = fmaf(xv.x, w00, acc0[r]);
            acc1[r] = fmaf(xv.x, w10, acc1[r]);
            acc0[r] = fmaf(xv.y, w01, acc0[r]);
            acc1[r] = fmaf(xv.y, w11, acc1[r]);
            acc0[r] = fmaf(xv.z, w02, acc0[r]);
            acc1[r] = fmaf(xv.z, w12, acc1[r]);
            acc0[r] = fmaf(xv.w, w03, acc0[r]);
            acc1[r] = fmaf(xv.w, w13, acc1[r]);
        }
    }
    float b0 = bias[c0], b1 = bias[c1];
    #pragma unroll
    for (int r = 0; r < 16; ++r) {
        int gr = row0 + rbase + r;
        if (gr < n) {
            float v0 = acc0[r] + b0, v1 = acc1[r] + b1;
            if (do_relu) { v0 = fmaxf(v0, 0.f); v1 = fmaxf(v1, 0.f); }
            out[(size_t)gr * 128 + c0] = v0;
            out[(size_t)gr * 128 + c1] = v1;
        }
    }
}

// y[r][c] = rowscale[r] * xin[r][:] @ W3[:,c], c < 40 (padded to 64 lanes). No bias/relu.
__global__ __launch_bounds__(256) void mm40_kernel(const float* __restrict__ xin,
        const float* __restrict__ W, const float* __restrict__ rowscale,
        float* __restrict__ out, int n) {
    __shared__ float Wl[128 * 64];
    __shared__ float Xl[64][128];
    int t = threadIdx.x;
    for (int i = t; i < 128 * 64; i += 256) {
        int k = i >> 6, c = i & 63;
        Wl[i] = (c < 40) ? W[k * 40 + c] : 0.f;
    }
    int row0 = blockIdx.x * 64;
    for (int i = t; i < 64 * 32; i += 256) {
        int r = i >> 5, k4 = i & 31;
        int gr = row0 + r;
        float4 xv;
        if (gr < n) {
            xv = reinterpret_cast<const float4*>(xin)[(size_t)gr * 32 + k4];
            float sc = rowscale[gr];
            xv.x *= sc; xv.y *= sc; xv.z *= sc; xv.w *= sc;
        } else { xv = make_float4(0.f, 0.f, 0.f, 0.f); }
        reinterpret_cast<float4*>(&Xl[r][0])[k4] = xv;
    }
    __syncthreads();
    int wv = t >> 6, lane = t & 63;
    float acc[16];
    #pragma unroll
    for (int r = 0; r < 16; ++r) acc[r] = 0.f;
    int rbase = wv * 16;
    for (int k = 0; k < 128; k += 2) {
        float w0 = Wl[(k + 0) * 64 + lane];
        float w1 = Wl[(k + 1) * 64 + lane];
        #pragma unroll
        for (int r = 0; r < 16; ++r) {
            float2 xv = *reinterpret_cast<const float2*>(&Xl[rbase + r][k]);
            acc[r] = fmaf(xv.x, w0, acc[r]);
            acc[r] = fmaf(xv.y, w1, acc[r]);
        }
    }
    if (lane < 40) {
        #pragma unroll
        for (int r = 0; r < 16; ++r) {
            int gr = row0 + rbase + r;
            if (gr < n) out[(size_t)gr * 40 + lane] = acc[r];
        }
    }
}

// out[v][c] = norm_dst[v] * sum_{u->v} y[u][c] + b3[c], c < 40. One wave/node.
__global__ __launch_bounds__(256) void agg40_kernel(const float* __restrict__ y,
        const int* __restrict__ row_ptr, const int* __restrict__ col,
        const float* __restrict__ norm_dst, const float* __restrict__ b3,
        float* __restrict__ out, int n) {
    int wid  = (blockIdx.x * blockDim.x + threadIdx.x) >> 6;
    int lane = threadIdx.x & 63;
    if (wid >= n) return;
    int start = row_ptr[wid], end = row_ptr[wid + 1];
    float acc = 0.f;
    for (int b = start; b < end; b += 64) {
        int m = end - b; if (m > 64) m = 64;
        int u = 0;
        if (lane < m) u = col[b + lane];
        for (int j = 0; j < m; ++j) {
            int uu = __shfl(u, j);
            if (lane < 40) acc += y[(size_t)uu * 40 + lane];
        }
    }
    if (lane < 40) out[(size_t)wid * 40 + lane] = norm_dst[wid] * acc + b3[lane];
}

extern "C" void kernel_launch(void* const* d_in, const int* in_sizes, int n_in,
                              void* d_out, int out_size, void* d_ws, size_t ws_size,
                              hipStream_t stream) {
    const float* features = (const float*)d_in[0];
    const int*   ei       = (const int*)d_in[1];
    const float* W1 = (const float*)d_in[2];
    const float* b1 = (const float*)d_in[3];
    const float* W2 = (const float*)d_in[4];
    const float* b2 = (const float*)d_in[5];
    const float* W3 = (const float*)d_in[6];
    const float* b3 = (const float*)d_in[7];

    const int n = in_sizes[0] / 128;
    const int E = in_sizes[1] / 2;

    char* w = (char*)d_ws;
    auto alloc = [&](size_t bytes) {
        char* p = w;
        w += (bytes + 255) & ~(size_t)255;
        return p;
    };
    int*   deg      = (int*)  alloc((size_t)2 * n * 4);  // deg_out | deg_in
    float* norm_src = (float*)alloc((size_t)n * 4);
    float* norm_dst = (float*)alloc((size_t)n * 4);
    int*   row_ptr  = (int*)  alloc((size_t)(n + 1) * 4);
    int*   cursor   = (int*)  alloc((size_t)n * 4);
    int*   partials = (int*)  alloc((size_t)256 * 4);
    int*   col      = (int*)  alloc((size_t)E * 4);
    float* bufA     = (float*)alloc((size_t)n * 128 * 4);
    float* bufB     = (float*)alloc((size_t)n * 128 * 4);

    int* deg_out = deg;
    int* deg_in  = deg + n;

    hipMemsetAsync(deg, 0, (size_t)2 * n * 4, stream);

    int eb = (E + 255) / 256;
    int sb = (n + SCAN_CHUNK - 1) / SCAN_CHUNK;  // scan blocks (13 for n=50k)

    degree_kernel<<<eb, 256, 0, stream>>>(ei, E, deg_out, deg_in);
    scan_blocksum<<<sb, 256, 0, stream>>>(deg_in, n, partials);
    scan_partials<<<1, 256, 0, stream>>>(partials, sb, row_ptr, n);
    scan_emit<<<sb, 256, 0, stream>>>(deg_in, deg_out, partials, n,
                                      row_ptr, cursor, norm_src, norm_dst);
    fill_kernel<<<eb, 256, 0, stream>>>(ei, E, cursor, col);

    int ab = (n + 3) / 4;    // 4 node-waves per 256-thread block
    int mb = (n + 63) / 64;  // 64 rows per matmul block

    agg128_kernel<<<ab, 256, 0, stream>>>(features, row_ptr, col, norm_src, bufA, n);
    mm128_kernel<<<mb, 256, 0, stream>>>(bufA, W1, b1, norm_dst, bufB, n, 1);
    agg128_kernel<<<ab, 256, 0, stream>>>(bufB, row_ptr, col, norm_src, bufA, n);
    mm128_kernel<<<mb, 256, 0, stream>>>(bufA, W2, b2, norm_dst, bufB, n, 1);
    mm40_kernel<<<mb, 256, 0, stream>>>(bufB, W3, norm_src, bufA, n);
    agg40_kernel<<<ab, 256, 0, stream>>>(bufA, row_ptr, col, norm_dst, b3, (float*)d_out, n);
}

// Round 3
// 440.801 us; speedup vs baseline: 1.4127x; 1.2028x over previous
//
#include <hip/hip_runtime.h>

// GCN 3-layer forward on MI355X.
// Per-call CSR build (by dst) with hierarchical scan, then per-layer:
//   agg[v] = sum_{u->v} norm_src[u] * x[u]   (wave-per-node, register accum)
//   h = relu(norm_dst[v] * agg @ W + b)      (LDS X-tile, W streamed from L2)
// Layer 3 swaps order: y = (norm_src*h2)@W3 first (128->40), then 40-dim agg.

#define SCAN_CHUNK 4096  // elements per scan block (256 threads x 16)

__global__ void degree_kernel(const int* __restrict__ ei, int E,
                              int* __restrict__ deg_out, int* __restrict__ deg_in) {
    int e = blockIdx.x * blockDim.x + threadIdx.x;
    if (e < E) {
        atomicAdd(&deg_out[ei[e]], 1);
        atomicAdd(&deg_in[ei[E + e]], 1);
    }
}

// Phase 1: coalesced per-block sums of deg_in.
__global__ __launch_bounds__(256) void scan_blocksum(const int* __restrict__ deg_in, int n,
                                                     int* __restrict__ partials) {
    __shared__ int red[256];
    int t = threadIdx.x;
    int base = blockIdx.x * SCAN_CHUNK;
    int s = 0;
    for (int i = t; i < SCAN_CHUNK; i += 256) {
        int idx = base + i;
        if (idx < n) s += deg_in[idx];
    }
    red[t] = s;
    __syncthreads();
    for (int off = 128; off > 0; off >>= 1) {
        if (t < off) red[t] += red[t + off];
        __syncthreads();
    }
    if (t == 0) partials[blockIdx.x] = red[0];
}

// Phase 2: exclusive scan of partials (nparts <= 256) + write row_ptr[n].
__global__ __launch_bounds__(256) void scan_partials(int* __restrict__ partials, int nparts,
                                                     int* __restrict__ row_ptr, int n) {
    __shared__ int s[256];
    int t = threadIdx.x;
    s[t] = (t < nparts) ? partials[t] : 0;
    __syncthreads();
    for (int off = 1; off < 256; off <<= 1) {
        int v = (t >= off) ? s[t - off] : 0;
        __syncthreads();
        s[t] += v;
        __syncthreads();
    }
    int incl = s[t];
    int excl = incl - ((t < nparts) ? partials[t] : 0);
    if (t < nparts) partials[t] = excl;
    if (t == 255) row_ptr[n] = incl;  // total (tail of s is zero-padded)
}

// Phase 3: per-chunk exclusive scan + emit row_ptr/cursor + fused norm compute.
__global__ __launch_bounds__(256) void scan_emit(const int* __restrict__ deg_in,
                                                 const int* __restrict__ deg_out,
                                                 const int* __restrict__ partials, int n,
                                                 int* __restrict__ row_ptr, int* __restrict__ cursor,
                                                 float* __restrict__ norm_src,
                                                 float* __restrict__ norm_dst) {
    __shared__ int tsum[256];
    int t = threadIdx.x;
    int base = blockIdx.x * SCAN_CHUNK + t * 16;
    int local[16];
    int s = 0;
    #pragma unroll
    for (int i = 0; i < 16; ++i) {
        int idx = base + i;
        int v = (idx < n) ? deg_in[idx] : 0;
        local[i] = v;
        s += v;
    }
    tsum[t] = s;
    __syncthreads();
    for (int off = 1; off < 256; off <<= 1) {
        int v = (t >= off) ? tsum[t - off] : 0;
        __syncthreads();
        tsum[t] += v;
        __syncthreads();
    }
    int run = partials[blockIdx.x] + (t ? tsum[t - 1] : 0);
    #pragma unroll
    for (int i = 0; i < 16; ++i) {
        int idx = base + i;
        if (idx < n) {
            row_ptr[idx] = run;
            cursor[idx]  = run;
            run += local[i];
            int di = local[i] > 0 ? local[i] : 1;
            int dq = deg_out[idx] > 0 ? deg_out[idx] : 1;
            norm_dst[idx] = rsqrtf((float)di);
            norm_src[idx] = rsqrtf((float)dq);
        }
    }
}

__global__ void fill_kernel(const int* __restrict__ ei, int E,
                            int* __restrict__ cursor, int* __restrict__ col) {
    int e = blockIdx.x * blockDim.x + threadIdx.x;
    if (e < E) {
        int s = ei[e];
        int d = ei[E + e];
        int slot = atomicAdd(&cursor[d], 1);
        col[slot] = s;
    }
}

// One wave per node: acc[v][:] = sum_{u in in(v)} norm_src[u] * x[u][:], D=128.
// Lane l holds dims 2l, 2l+1 (float2). Edge ids batched 64/wave via shfl.
__global__ __launch_bounds__(256) void agg128_kernel(const float* __restrict__ x,
        const int* __restrict__ row_ptr, const int* __restrict__ col,
        const float* __restrict__ norm_src, float* __restrict__ out, int n) {
    int wid  = (blockIdx.x * blockDim.x + threadIdx.x) >> 6;
    int lane = threadIdx.x & 63;
    if (wid >= n) return;
    int start = row_ptr[wid], end = row_ptr[wid + 1];
    float a0 = 0.f, a1 = 0.f;
    for (int b = start; b < end; b += 64) {
        int m = end - b; if (m > 64) m = 64;
        int u = 0; float s = 0.f;
        if (lane < m) { u = col[b + lane]; s = norm_src[u]; }
        for (int j = 0; j < m; ++j) {
            int   uu = __shfl(u, j);
            float ss = __shfl(s, j);
            const float2 xv = *reinterpret_cast<const float2*>(&x[(size_t)uu * 128 + 2 * lane]);
            a0 = fmaf(ss, xv.x, a0);
            a1 = fmaf(ss, xv.y, a1);
        }
    }
    float2 o; o.x = a0; o.y = a1;
    *reinterpret_cast<float2*>(&out[(size_t)wid * 128 + 2 * lane]) = o;
}

// out[r][:] = relu( rowscale[r] * xin[r][:] @ W + b ), W is 128x128 row-major.
// 64 rows/block; X tile (32KB) in LDS; W streamed from global (L2-resident).
// Wave w -> rows w*16..+15, lane -> cols (lane, lane+64).
__global__ __launch_bounds__(256, 4) void mm128_kernel(const float* __restrict__ xin,
        const float* __restrict__ W, const float* __restrict__ bias,
        const float* __restrict__ rowscale, float* __restrict__ out, int n, int do_relu) {
    __shared__ float Xl[64][128];
    int t = threadIdx.x;
    int row0 = blockIdx.x * 64;
    for (int i = t; i < 64 * 32; i += 256) {
        int r = i >> 5, k4 = i & 31;
        int gr = row0 + r;
        float4 xv = make_float4(0.f, 0.f, 0.f, 0.f);
        if (gr < n) {
            xv = reinterpret_cast<const float4*>(xin)[(size_t)gr * 32 + k4];
            float sc = rowscale[gr];
            xv.x *= sc; xv.y *= sc; xv.z *= sc; xv.w *= sc;
        }
        reinterpret_cast<float4*>(&Xl[r][0])[k4] = xv;
    }
    __syncthreads();
    int wv = t >> 6, lane = t & 63;
    int c0 = lane, c1 = lane + 64;
    float acc0[16], acc1[16];
    #pragma unroll
    for (int r = 0; r < 16; ++r) { acc0[r] = 0.f; acc1[r] = 0.f; }
    int rbase = wv * 16;
    const float* Wp0 = W + c0;
    const float* Wp1 = W + c1;
    for (int k = 0; k < 128; k += 4) {
        float w00 = Wp0[(k + 0) * 128], w10 = Wp1[(k + 0) * 128];
        float w01 = Wp0[(k + 1) * 128], w11 = Wp1[(k + 1) * 128];
        float w02 = Wp0[(k + 2) * 128], w12 = Wp1[(k + 2) * 128];
        float w03 = Wp0[(k + 3) * 128], w13 = Wp1[(k + 3) * 128];
        #pragma unroll
        for (int r = 0; r < 16; ++r) {
            float4 xv = *reinterpret_cast<const float4*>(&Xl[rbase + r][k]);
            acc0[r] = fmaf(xv.x, w00, acc0[r]);
            acc1[r] = fmaf(xv.x, w10, acc1[r]);
            acc0[r] = fmaf(xv.y, w01, acc0[r]);
            acc1[r] = fmaf(xv.y, w11, acc1[r]);
            acc0[r] = fmaf(xv.z, w02, acc0[r]);
            acc1[r] = fmaf(xv.z, w12, acc1[r]);
            acc0[r] = fmaf(xv.w, w03, acc0[r]);
            acc1[r] = fmaf(xv.w, w13, acc1[r]);
        }
    }
    float b0 = bias[c0], b1 = bias[c1];
    #pragma unroll
    for (int r = 0; r < 16; ++r) {
        int gr = row0 + rbase + r;
        if (gr < n) {
            float v0 = acc0[r] + b0, v1 = acc1[r] + b1;
            if (do_relu) { v0 = fmaxf(v0, 0.f); v1 = fmaxf(v1, 0.f); }
            out[(size_t)gr * 128 + c0] = v0;
            out[(size_t)gr * 128 + c1] = v1;
        }
    }
}

// y[r][c] = rowscale[r] * xin[r][:] @ W3[:,c], c < 40. W3 streamed from global.
__global__ __launch_bounds__(256, 4) void mm40_kernel(const float* __restrict__ xin,
        const float* __restrict__ W, const float* __restrict__ rowscale,
        float* __restrict__ out, int n) {
    __shared__ float Xl[64][128];
    int t = threadIdx.x;
    int row0 = blockIdx.x * 64;
    for (int i = t; i < 64 * 32; i += 256) {
        int r = i >> 5, k4 = i & 31;
        int gr = row0 + r;
        float4 xv = make_float4(0.f, 0.f, 0.f, 0.f);
        if (gr < n) {
            xv = reinterpret_cast<const float4*>(xin)[(size_t)gr * 32 + k4];
            float sc = rowscale[gr];
            xv.x *= sc; xv.y *= sc; xv.z *= sc; xv.w *= sc;
        }
        reinterpret_cast<float4*>(&Xl[r][0])[k4] = xv;
    }
    __syncthreads();
    int wv = t >> 6, lane = t & 63;
    int c = (lane < 40) ? lane : 0;  // clamp; lanes >=40 compute col 0, masked at store
    float acc[16];
    #pragma unroll
    for (int r = 0; r < 16; ++r) acc[r] = 0.f;
    int rbase = wv * 16;
    const float* Wp = W + c;
    for (int k = 0; k < 128; k += 2) {
        float w0 = Wp[(k + 0) * 40];
        float w1 = Wp[(k + 1) * 40];
        #pragma unroll
        for (int r = 0; r < 16; ++r) {
            float2 xv = *reinterpret_cast<const float2*>(&Xl[rbase + r][k]);
            acc[r] = fmaf(xv.x, w0, acc[r]);
            acc[r] = fmaf(xv.y, w1, acc[r]);
        }
    }
    if (lane < 40) {
        #pragma unroll
        for (int r = 0; r < 16; ++r) {
            int gr = row0 + rbase + r;
            if (gr < n) out[(size_t)gr * 40 + lane] = acc[r];
        }
    }
}

// out[v][c] = norm_dst[v] * sum_{u->v} y[u][c] + b3[c], c < 40. One wave/node.
__global__ __launch_bounds__(256) void agg40_kernel(const float* __restrict__ y,
        const int* __restrict__ row_ptr, const int* __restrict__ col,
        const float* __restrict__ norm_dst, const float* __restrict__ b3,
        float* __restrict__ out, int n) {
    int wid  = (blockIdx.x * blockDim.x + threadIdx.x) >> 6;
    int lane = threadIdx.x & 63;
    if (wid >= n) return;
    int start = row_ptr[wid], end = row_ptr[wid + 1];
    float acc = 0.f;
    for (int b = start; b < end; b += 64) {
        int m = end - b; if (m > 64) m = 64;
        int u = 0;
        if (lane < m) u = col[b + lane];
        for (int j = 0; j < m; ++j) {
            int uu = __shfl(u, j);
            if (lane < 40) acc += y[(size_t)uu * 40 + lane];
        }
    }
    if (lane < 40) out[(size_t)wid * 40 + lane] = norm_dst[wid] * acc + b3[lane];
}

extern "C" void kernel_launch(void* const* d_in, const int* in_sizes, int n_in,
                              void* d_out, int out_size, void* d_ws, size_t ws_size,
                              hipStream_t stream) {
    const float* features = (const float*)d_in[0];
    const int*   ei       = (const int*)d_in[1];
    const float* W1 = (const float*)d_in[2];
    const float* b1 = (const float*)d_in[3];
    const float* W2 = (const float*)d_in[4];
    const float* b2 = (const float*)d_in[5];
    const float* W3 = (const float*)d_in[6];
    const float* b3 = (const float*)d_in[7];

    const int n = in_sizes[0] / 128;
    const int E = in_sizes[1] / 2;

    char* w = (char*)d_ws;
    auto alloc = [&](size_t bytes) {
        char* p = w;
        w += (bytes + 255) & ~(size_t)255;
        return p;
    };
    int*   deg      = (int*)  alloc((size_t)2 * n * 4);  // deg_out | deg_in
    float* norm_src = (float*)alloc((size_t)n * 4);
    float* norm_dst = (float*)alloc((size_t)n * 4);
    int*   row_ptr  = (int*)  alloc((size_t)(n + 1) * 4);
    int*   cursor   = (int*)  alloc((size_t)n * 4);
    int*   partials = (int*)  alloc((size_t)256 * 4);
    int*   col      = (int*)  alloc((size_t)E * 4);
    float* bufA     = (float*)alloc((size_t)n * 128 * 4);
    float* bufB     = (float*)alloc((size_t)n * 128 * 4);

    int* deg_out = deg;
    int* deg_in  = deg + n;

    hipMemsetAsync(deg, 0, (size_t)2 * n * 4, stream);

    int eb = (E + 255) / 256;
    int sb = (n + SCAN_CHUNK - 1) / SCAN_CHUNK;  // scan blocks (13 for n=50k)

    degree_kernel<<<eb, 256, 0, stream>>>(ei, E, deg_out, deg_in);
    scan_blocksum<<<sb, 256, 0, stream>>>(deg_in, n, partials);
    scan_partials<<<1, 256, 0, stream>>>(partials, sb, row_ptr, n);
    scan_emit<<<sb, 256, 0, stream>>>(deg_in, deg_out, partials, n,
                                      row_ptr, cursor, norm_src, norm_dst);
    fill_kernel<<<eb, 256, 0, stream>>>(ei, E, cursor, col);

    int ab = (n + 3) / 4;    // 4 node-waves per 256-thread block
    int mb = (n + 63) / 64;  // 64 rows per matmul block

    agg128_kernel<<<ab, 256, 0, stream>>>(features, row_ptr, col, norm_src, bufA, n);
    mm128_kernel<<<mb, 256, 0, stream>>>(bufA, W1, b1, norm_dst, bufB, n, 1);
    agg128_kernel<<<ab, 256, 0, stream>>>(bufB, row_ptr, col, norm_src, bufA, n);
    mm128_kernel<<<mb, 256, 0, stream>>>(bufA, W2, b2, norm_dst, bufB, n, 1);
    mm40_kernel<<<mb, 256, 0, stream>>>(bufB, W3, norm_src, bufA, n);
    agg40_kernel<<<ab, 256, 0, stream>>>(bufA, row_ptr, col, norm_dst, b3, (float*)d_out, n);
}

// Round 4
// 373.588 us; speedup vs baseline: 1.6668x; 1.1799x over previous
//
#include <hip/hip_runtime.h>

// GCN 3-layer forward on MI355X.
// CSR build (by dst) with hierarchical scan, then per-layer:
//   xb[u] = bf16(norm_src[u] * x[u])          (pre-scaled bf16 node table)
//   agg[v] = sum_{u->v} xb[u]                 (pure bf16 gather-sum, fp32 accum)
//   h' = bf16( ns * relu(nd * agg @ W + b) )  (next layer's pre-scaled table)
// Layer 3: y = h2' @ W3 (fp32), then 40-dim agg with nd + b3.

#define SCAN_CHUNK 4096

__device__ __forceinline__ ushort f2bf(float f) {
    unsigned u = __float_as_uint(f);
    unsigned r = (u + 0x7fffu + ((u >> 16) & 1u)) >> 16;  // RN-even
    return (ushort)r;
}
__device__ __forceinline__ void unpack2(unsigned w, float& lo, float& hi) {
    lo = __uint_as_float(w << 16);
    hi = __uint_as_float(w & 0xffff0000u);
}

__global__ void degree_kernel(const int* __restrict__ ei, int E,
                              int* __restrict__ deg_out, int* __restrict__ deg_in) {
    int e = blockIdx.x * blockDim.x + threadIdx.x;
    if (e < E) {
        atomicAdd(&deg_out[ei[e]], 1);
        atomicAdd(&deg_in[ei[E + e]], 1);
    }
}

__global__ __launch_bounds__(256) void scan_blocksum(const int* __restrict__ deg_in, int n,
                                                     int* __restrict__ partials) {
    __shared__ int red[256];
    int t = threadIdx.x;
    int base = blockIdx.x * SCAN_CHUNK;
    int s = 0;
    for (int i = t; i < SCAN_CHUNK; i += 256) {
        int idx = base + i;
        if (idx < n) s += deg_in[idx];
    }
    red[t] = s;
    __syncthreads();
    for (int off = 128; off > 0; off >>= 1) {
        if (t < off) red[t] += red[t + off];
        __syncthreads();
    }
    if (t == 0) partials[blockIdx.x] = red[0];
}

__global__ __launch_bounds__(256) void scan_partials(int* __restrict__ partials, int nparts,
                                                     int* __restrict__ row_ptr, int n) {
    __shared__ int s[256];
    int t = threadIdx.x;
    s[t] = (t < nparts) ? partials[t] : 0;
    __syncthreads();
    for (int off = 1; off < 256; off <<= 1) {
        int v = (t >= off) ? s[t - off] : 0;
        __syncthreads();
        s[t] += v;
        __syncthreads();
    }
    int incl = s[t];
    int excl = incl - ((t < nparts) ? partials[t] : 0);
    if (t < nparts) partials[t] = excl;
    if (t == 255) row_ptr[n] = incl;
}

__global__ __launch_bounds__(256) void scan_emit(const int* __restrict__ deg_in,
                                                 const int* __restrict__ deg_out,
                                                 const int* __restrict__ partials, int n,
                                                 int* __restrict__ row_ptr, int* __restrict__ cursor,
                                                 float* __restrict__ norm_src,
                                                 float* __restrict__ norm_dst) {
    __shared__ int tsum[256];
    int t = threadIdx.x;
    int base = blockIdx.x * SCAN_CHUNK + t * 16;
    int local[16];
    int s = 0;
    #pragma unroll
    for (int i = 0; i < 16; ++i) {
        int idx = base + i;
        int v = (idx < n) ? deg_in[idx] : 0;
        local[i] = v;
        s += v;
    }
    tsum[t] = s;
    __syncthreads();
    for (int off = 1; off < 256; off <<= 1) {
        int v = (t >= off) ? tsum[t - off] : 0;
        __syncthreads();
        tsum[t] += v;
        __syncthreads();
    }
    int run = partials[blockIdx.x] + (t ? tsum[t - 1] : 0);
    #pragma unroll
    for (int i = 0; i < 16; ++i) {
        int idx = base + i;
        if (idx < n) {
            row_ptr[idx] = run;
            cursor[idx]  = run;
            run += local[i];
            int di = local[i] > 0 ? local[i] : 1;
            int dq = deg_out[idx] > 0 ? deg_out[idx] : 1;
            norm_dst[idx] = rsqrtf((float)di);
            norm_src[idx] = rsqrtf((float)dq);
        }
    }
}

// xb[row][:] = bf16(ns[row] * x[row][:]); 4 elems/thread.
__global__ __launch_bounds__(256) void convert_kernel(const float* __restrict__ x,
        const float* __restrict__ ns, ushort* __restrict__ xb, int n) {
    int i = blockIdx.x * blockDim.x + threadIdx.x;
    if (i >= n * 32) return;
    int row = i >> 5;
    float s = ns[row];
    float4 v = reinterpret_cast<const float4*>(x)[i];
    ushort4 o;
    o.x = f2bf(v.x * s); o.y = f2bf(v.y * s);
    o.z = f2bf(v.z * s); o.w = f2bf(v.w * s);
    reinterpret_cast<ushort4*>(xb)[i] = o;
}

__global__ void fill_kernel(const int* __restrict__ ei, int E,
                            int* __restrict__ cursor, int* __restrict__ col) {
    int e = blockIdx.x * blockDim.x + threadIdx.x;
    if (e < E) {
        int s = ei[e];
        int d = ei[E + e];
        int slot = atomicAdd(&cursor[d], 1);
        col[slot] = s;
    }
}

// One wave per node: out[v][:] = sum_{u->v} xb[u][:] (bf16 rows, fp32 accum).
// 4 edges per iteration: 16 lanes x 8 dims each (16B loads); quarter-wave combine at end.
__global__ __launch_bounds__(256) void agg128_kernel(const ushort* __restrict__ xb,
        const int* __restrict__ row_ptr, const int* __restrict__ col,
        float* __restrict__ out, int n) {
    int wid  = (blockIdx.x * blockDim.x + threadIdx.x) >> 6;
    int lane = threadIdx.x & 63;
    if (wid >= n) return;
    int start = row_ptr[wid], end = row_ptr[wid + 1];
    int quarter = lane >> 4, l4 = lane & 15;
    float acc[8];
    #pragma unroll
    for (int i = 0; i < 8; ++i) acc[i] = 0.f;
    for (int b = start; b < end; b += 64) {
        int m = end - b; if (m > 64) m = 64;
        int u = 0;
        if (lane < m) u = col[b + lane];
        for (int j = 0; j < m; j += 4) {
            int jj = j + quarter;
            int uu = __shfl(u, jj);
            if (jj < m) {
                const uint4 v = *reinterpret_cast<const uint4*>(xb + (size_t)uu * 128 + 8 * l4);
                float f0, f1;
                unpack2(v.x, f0, f1); acc[0] += f0; acc[1] += f1;
                unpack2(v.y, f0, f1); acc[2] += f0; acc[3] += f1;
                unpack2(v.z, f0, f1); acc[4] += f0; acc[5] += f1;
                unpack2(v.w, f0, f1); acc[6] += f0; acc[7] += f1;
            }
        }
    }
    #pragma unroll
    for (int i = 0; i < 8; ++i) {
        acc[i] += __shfl_xor(acc[i], 16);
        acc[i] += __shfl_xor(acc[i], 32);
    }
    if (lane < 16) {
        float* op = out + (size_t)wid * 128 + 8 * lane;
        *reinterpret_cast<float4*>(op)     = make_float4(acc[0], acc[1], acc[2], acc[3]);
        *reinterpret_cast<float4*>(op + 4) = make_float4(acc[4], acc[5], acc[6], acc[7]);
    }
}

// out[r][:] = bf16( ns[r] * relu( nd[r] * (xin[r][:] @ W) + b ) ), W 128x128 row-major.
// X tile (32KB) in LDS; W streamed from L2. Wave w -> rows w*16..+15, lane -> cols lane,lane+64.
__global__ __launch_bounds__(256, 4) void mm128_kernel(const float* __restrict__ xin,
        const float* __restrict__ W, const float* __restrict__ bias,
        const float* __restrict__ norm_dst, const float* __restrict__ norm_src,
        ushort* __restrict__ out, int n) {
    __shared__ float Xl[64][128];
    int t = threadIdx.x;
    int row0 = blockIdx.x * 64;
    for (int i = t; i < 64 * 32; i += 256) {
        int r = i >> 5, k4 = i & 31;
        int gr = row0 + r;
        float4 xv = make_float4(0.f, 0.f, 0.f, 0.f);
        if (gr < n) xv = reinterpret_cast<const float4*>(xin)[(size_t)gr * 32 + k4];
        reinterpret_cast<float4*>(&Xl[r][0])[k4] = xv;
    }
    __syncthreads();
    int wv = t >> 6, lane = t & 63;
    int c0 = lane, c1 = lane + 64;
    float acc0[16], acc1[16];
    #pragma unroll
    for (int r = 0; r < 16; ++r) { acc0[r] = 0.f; acc1[r] = 0.f; }
    int rbase = wv * 16;
    const float* Wp0 = W + c0;
    const float* Wp1 = W + c1;
    for (int k = 0; k < 128; k += 4) {
        float w00 = Wp0[(k + 0) * 128], w10 = Wp1[(k + 0) * 128];
        float w01 = Wp0[(k + 1) * 128], w11 = Wp1[(k + 1) * 128];
        float w02 = Wp0[(k + 2) * 128], w12 = Wp1[(k + 2) * 128];
        float w03 = Wp0[(k + 3) * 128], w13 = Wp1[(k + 3) * 128];
        #pragma unroll
        for (int r = 0; r < 16; ++r) {
            float4 xv = *reinterpret_cast<const float4*>(&Xl[rbase + r][k]);
            acc0[r] = fmaf(xv.x, w00, acc0[r]);
            acc1[r] = fmaf(xv.x, w10, acc1[r]);
            acc0[r] = fmaf(xv.y, w01, acc0[r]);
            acc1[r] = fmaf(xv.y, w11, acc1[r]);
            acc0[r] = fmaf(xv.z, w02, acc0[r]);
            acc1[r] = fmaf(xv.z, w12, acc1[r]);
            acc0[r] = fmaf(xv.w, w03, acc0[r]);
            acc1[r] = fmaf(xv.w, w13, acc1[r]);
        }
    }
    float b0 = bias[c0], b1 = bias[c1];
    #pragma unroll
    for (int r = 0; r < 16; ++r) {
        int gr = row0 + rbase + r;
        if (gr < n) {
            float nd = norm_dst[gr], ns = norm_src[gr];
            float v0 = fmaxf(fmaf(nd, acc0[r], b0), 0.f) * ns;
            float v1 = fmaxf(fmaf(nd, acc1[r], b1), 0.f) * ns;
            out[(size_t)gr * 128 + c0] = f2bf(v0);
            out[(size_t)gr * 128 + c1] = f2bf(v1);
        }
    }
}

// y[r][c] = xin_bf16[r][:] @ W3[:,c], c < 40 (input already ns-prescaled). fp32 out.
__global__ __launch_bounds__(256, 4) void mm40_kernel(const ushort* __restrict__ xin,
        const float* __restrict__ W, float* __restrict__ out, int n) {
    __shared__ float Xl[64][128];
    int t = threadIdx.x;
    int row0 = blockIdx.x * 64;
    for (int i = t; i < 1024; i += 256) {
        int r = i >> 4, c8 = i & 15;
        int gr = row0 + r;
        float4 a0 = make_float4(0.f, 0.f, 0.f, 0.f);
        float4 a1 = make_float4(0.f, 0.f, 0.f, 0.f);
        if (gr < n) {
            uint4 v = *reinterpret_cast<const uint4*>(xin + (size_t)gr * 128 + 8 * c8);
            unpack2(v.x, a0.x, a0.y); unpack2(v.y, a0.z, a0.w);
            unpack2(v.z, a1.x, a1.y); unpack2(v.w, a1.z, a1.w);
        }
        float4* lp = reinterpret_cast<float4*>(&Xl[r][8 * c8]);
        lp[0] = a0; lp[1] = a1;
    }
    __syncthreads();
    int wv = t >> 6, lane = t & 63;
    int c = (lane < 40) ? lane : 0;
    float acc[16];
    #pragma unroll
    for (int r = 0; r < 16; ++r) acc[r] = 0.f;
    int rbase = wv * 16;
    const float* Wp = W + c;
    for (int k = 0; k < 128; k += 2) {
        float w0 = Wp[(k + 0) * 40];
        float w1 = Wp[(k + 1) * 40];
        #pragma unroll
        for (int r = 0; r < 16; ++r) {
            float2 xv = *reinterpret_cast<const float2*>(&Xl[rbase + r][k]);
            acc[r] = fmaf(xv.x, w0, acc[r]);
            acc[r] = fmaf(xv.y, w1, acc[r]);
        }
    }
    if (lane < 40) {
        #pragma unroll
        for (int r = 0; r < 16; ++r) {
            int gr = row0 + rbase + r;
            if (gr < n) out[(size_t)gr * 40 + lane] = acc[r];
        }
    }
}

// out[v][c] = norm_dst[v] * sum_{u->v} y[u][c] + b3[c], c < 40. One wave/node.
__global__ __launch_bounds__(256) void agg40_kernel(const float* __restrict__ y,
        const int* __restrict__ row_ptr, const int* __restrict__ col,
        const float* __restrict__ norm_dst, const float* __restrict__ b3,
        float* __restrict__ out, int n) {
    int wid  = (blockIdx.x * blockDim.x + threadIdx.x) >> 6;
    int lane = threadIdx.x & 63;
    if (wid >= n) return;
    int start = row_ptr[wid], end = row_ptr[wid + 1];
    float acc = 0.f;
    for (int b = start; b < end; b += 64) {
        int m = end - b; if (m > 64) m = 64;
        int u = 0;
        if (lane < m) u = col[b + lane];
        for (int j = 0; j < m; ++j) {
            int uu = __shfl(u, j);
            if (lane < 40) acc += y[(size_t)uu * 40 + lane];
        }
    }
    if (lane < 40) out[(size_t)wid * 40 + lane] = norm_dst[wid] * acc + b3[lane];
}

extern "C" void kernel_launch(void* const* d_in, const int* in_sizes, int n_in,
                              void* d_out, int out_size, void* d_ws, size_t ws_size,
                              hipStream_t stream) {
    const float* features = (const float*)d_in[0];
    const int*   ei       = (const int*)d_in[1];
    const float* W1 = (const float*)d_in[2];
    const float* b1 = (const float*)d_in[3];
    const float* W2 = (const float*)d_in[4];
    const float* b2 = (const float*)d_in[5];
    const float* W3 = (const float*)d_in[6];
    const float* b3 = (const float*)d_in[7];

    const int n = in_sizes[0] / 128;
    const int E = in_sizes[1] / 2;

    char* w = (char*)d_ws;
    auto alloc = [&](size_t bytes) {
        char* p = w;
        w += (bytes + 255) & ~(size_t)255;
        return p;
    };
    int*    deg      = (int*)   alloc((size_t)2 * n * 4);
    float*  norm_src = (float*) alloc((size_t)n * 4);
    float*  norm_dst = (float*) alloc((size_t)n * 4);
    int*    row_ptr  = (int*)   alloc((size_t)(n + 1) * 4);
    int*    cursor   = (int*)   alloc((size_t)n * 4);
    int*    partials = (int*)   alloc((size_t)256 * 4);
    int*    col      = (int*)   alloc((size_t)E * 4);
    ushort* xb       = (ushort*)alloc((size_t)n * 128 * 2);  // bf16 node table (reused per layer)
    float*  bufA     = (float*) alloc((size_t)n * 128 * 4);  // fp32 agg / y buffer

    int* deg_out = deg;
    int* deg_in  = deg + n;

    hipMemsetAsync(deg, 0, (size_t)2 * n * 4, stream);

    int eb = (E + 255) / 256;
    int sb = (n + SCAN_CHUNK - 1) / SCAN_CHUNK;
    int cb = (n * 32 + 255) / 256;

    degree_kernel<<<eb, 256, 0, stream>>>(ei, E, deg_out, deg_in);
    scan_blocksum<<<sb, 256, 0, stream>>>(deg_in, n, partials);
    scan_partials<<<1, 256, 0, stream>>>(partials, sb, row_ptr, n);
    scan_emit<<<sb, 256, 0, stream>>>(deg_in, deg_out, partials, n,
                                      row_ptr, cursor, norm_src, norm_dst);
    convert_kernel<<<cb, 256, 0, stream>>>(features, norm_src, xb, n);
    fill_kernel<<<eb, 256, 0, stream>>>(ei, E, cursor, col);

    int ab = (n + 3) / 4;
    int mb = (n + 63) / 64;

    agg128_kernel<<<ab, 256, 0, stream>>>(xb, row_ptr, col, bufA, n);
    mm128_kernel<<<mb, 256, 0, stream>>>(bufA, W1, b1, norm_dst, norm_src, xb, n);
    agg128_kernel<<<ab, 256, 0, stream>>>(xb, row_ptr, col, bufA, n);
    mm128_kernel<<<mb, 256, 0, stream>>>(bufA, W2, b2, norm_dst, norm_src, xb, n);
    mm40_kernel<<<mb, 256, 0, stream>>>(xb, W3, bufA, n);
    agg40_kernel<<<ab, 256, 0, stream>>>(bufA, row_ptr, col, norm_dst, b3, (float*)d_out, n);
}

// Round 5
// 340.846 us; speedup vs baseline: 1.8269x; 1.0961x over previous
//
#include <hip/hip_runtime.h>

// GCN 3-layer forward on MI355X.
// CSR build (by dst): one combined count+slot atomic pass (the returning
// cursor atomic IS the histogram), hierarchical scan, atomic-free scatter.
// Per layer:
//   xb[u] = bf16(norm_src[u] * x[u])          (pre-scaled bf16 node table)
//   agg[v] = sum_{u->v} xb[u]                 (pure bf16 gather-sum, fp32 accum)
//   h' = bf16( ns * relu(nd * agg @ W + b) )  (next layer's pre-scaled table)
// Layer 3: y = h2' @ W3 (fp32), then 40-dim agg with nd + b3.

#define SCAN_CHUNK 4096

__device__ __forceinline__ ushort f2bf(float f) {
    unsigned u = __float_as_uint(f);
    unsigned r = (u + 0x7fffu + ((u >> 16) & 1u)) >> 16;  // RN-even
    return (ushort)r;
}
__device__ __forceinline__ void unpack2(unsigned w, float& lo, float& hi) {
    lo = __uint_as_float(w << 16);
    hi = __uint_as_float(w & 0xffff0000u);
}

// Combined histogram + slot assignment: 2 atomics per edge total.
// cnt_src -> deg_out; cnt_dst -> deg_in; tmp_slot[e] = within-dst-node slot.
__global__ __launch_bounds__(256) void count_slot_kernel(const int* __restrict__ ei, int E,
        int* __restrict__ cnt_src, int* __restrict__ cnt_dst, int* __restrict__ tmp_slot) {
    int base = (blockIdx.x * 256 + threadIdx.x) * 4;
    if (base + 3 < E) {
        int4 s4 = *reinterpret_cast<const int4*>(ei + base);
        int4 d4 = *reinterpret_cast<const int4*>(ei + E + base);
        atomicAdd(&cnt_src[s4.x], 1);
        atomicAdd(&cnt_src[s4.y], 1);
        atomicAdd(&cnt_src[s4.z], 1);
        atomicAdd(&cnt_src[s4.w], 1);
        int t0 = atomicAdd(&cnt_dst[d4.x], 1);
        int t1 = atomicAdd(&cnt_dst[d4.y], 1);
        int t2 = atomicAdd(&cnt_dst[d4.z], 1);
        int t3 = atomicAdd(&cnt_dst[d4.w], 1);
        *reinterpret_cast<int4*>(tmp_slot + base) = make_int4(t0, t1, t2, t3);
    } else {
        for (int e = base; e < E; ++e) {
            int s = ei[e], d = ei[E + e];
            atomicAdd(&cnt_src[s], 1);
            tmp_slot[e] = atomicAdd(&cnt_dst[d], 1);
        }
    }
}

// Atomic-free CSR placement: col[row_ptr[d] + tmp_slot[e]] = s.
__global__ __launch_bounds__(256) void scatter_kernel(const int* __restrict__ ei, int E,
        const int* __restrict__ row_ptr, const int* __restrict__ tmp_slot,
        int* __restrict__ col) {
    int base = (blockIdx.x * 256 + threadIdx.x) * 4;
    if (base + 3 < E) {
        int4 s4 = *reinterpret_cast<const int4*>(ei + base);
        int4 d4 = *reinterpret_cast<const int4*>(ei + E + base);
        int4 t4 = *reinterpret_cast<const int4*>(tmp_slot + base);
        col[row_ptr[d4.x] + t4.x] = s4.x;
        col[row_ptr[d4.y] + t4.y] = s4.y;
        col[row_ptr[d4.z] + t4.z] = s4.z;
        col[row_ptr[d4.w] + t4.w] = s4.w;
    } else {
        for (int e = base; e < E; ++e) {
            int s = ei[e], d = ei[E + e];
            col[row_ptr[d] + tmp_slot[e]] = s;
        }
    }
}

__global__ __launch_bounds__(256) void scan_blocksum(const int* __restrict__ deg_in, int n,
                                                     int* __restrict__ partials) {
    __shared__ int red[256];
    int t = threadIdx.x;
    int base = blockIdx.x * SCAN_CHUNK;
    int s = 0;
    for (int i = t; i < SCAN_CHUNK; i += 256) {
        int idx = base + i;
        if (idx < n) s += deg_in[idx];
    }
    red[t] = s;
    __syncthreads();
    for (int off = 128; off > 0; off >>= 1) {
        if (t < off) red[t] += red[t + off];
        __syncthreads();
    }
    if (t == 0) partials[blockIdx.x] = red[0];
}

__global__ __launch_bounds__(256) void scan_partials(int* __restrict__ partials, int nparts,
                                                     int* __restrict__ row_ptr, int n) {
    __shared__ int s[256];
    int t = threadIdx.x;
    s[t] = (t < nparts) ? partials[t] : 0;
    __syncthreads();
    for (int off = 1; off < 256; off <<= 1) {
        int v = (t >= off) ? s[t - off] : 0;
        __syncthreads();
        s[t] += v;
        __syncthreads();
    }
    int incl = s[t];
    int excl = incl - ((t < nparts) ? partials[t] : 0);
    if (t < nparts) partials[t] = excl;
    if (t == 255) row_ptr[n] = incl;
}

// Per-chunk exclusive scan -> row_ptr, fused norm compute.
__global__ __launch_bounds__(256) void scan_emit(const int* __restrict__ deg_in,
                                                 const int* __restrict__ deg_out,
                                                 const int* __restrict__ partials, int n,
                                                 int* __restrict__ row_ptr,
                                                 float* __restrict__ norm_src,
                                                 float* __restrict__ norm_dst) {
    __shared__ int tsum[256];
    int t = threadIdx.x;
    int base = blockIdx.x * SCAN_CHUNK + t * 16;
    int local[16];
    int s = 0;
    #pragma unroll
    for (int i = 0; i < 16; ++i) {
        int idx = base + i;
        int v = (idx < n) ? deg_in[idx] : 0;
        local[i] = v;
        s += v;
    }
    tsum[t] = s;
    __syncthreads();
    for (int off = 1; off < 256; off <<= 1) {
        int v = (t >= off) ? tsum[t - off] : 0;
        __syncthreads();
        tsum[t] += v;
        __syncthreads();
    }
    int run = partials[blockIdx.x] + (t ? tsum[t - 1] : 0);
    #pragma unroll
    for (int i = 0; i < 16; ++i) {
        int idx = base + i;
        if (idx < n) {
            row_ptr[idx] = run;
            run += local[i];
            int di = local[i] > 0 ? local[i] : 1;
            int dq = deg_out[idx] > 0 ? deg_out[idx] : 1;
            norm_dst[idx] = rsqrtf((float)di);
            norm_src[idx] = rsqrtf((float)dq);
        }
    }
}

// xb[row][:] = bf16(ns[row] * x[row][:]); 4 elems/thread.
__global__ __launch_bounds__(256) void convert_kernel(const float* __restrict__ x,
        const float* __restrict__ ns, ushort* __restrict__ xb, int n) {
    int i = blockIdx.x * blockDim.x + threadIdx.x;
    if (i >= n * 32) return;
    int row = i >> 5;
    float s = ns[row];
    float4 v = reinterpret_cast<const float4*>(x)[i];
    ushort4 o;
    o.x = f2bf(v.x * s); o.y = f2bf(v.y * s);
    o.z = f2bf(v.z * s); o.w = f2bf(v.w * s);
    reinterpret_cast<ushort4*>(xb)[i] = o;
}

// One wave per node: out[v][:] = sum_{u->v} xb[u][:] (bf16 rows, fp32 accum).
// 4 edges per iteration: 16 lanes x 8 dims each (16B loads); quarter-wave combine at end.
__global__ __launch_bounds__(256) void agg128_kernel(const ushort* __restrict__ xb,
        const int* __restrict__ row_ptr, const int* __restrict__ col,
        float* __restrict__ out, int n) {
    int wid  = (blockIdx.x * blockDim.x + threadIdx.x) >> 6;
    int lane = threadIdx.x & 63;
    if (wid >= n) return;
    int start = row_ptr[wid], end = row_ptr[wid + 1];
    int quarter = lane >> 4, l4 = lane & 15;
    float acc[8];
    #pragma unroll
    for (int i = 0; i < 8; ++i) acc[i] = 0.f;
    for (int b = start; b < end; b += 64) {
        int m = end - b; if (m > 64) m = 64;
        int u = 0;
        if (lane < m) u = col[b + lane];
        for (int j = 0; j < m; j += 4) {
            int jj = j + quarter;
            int uu = __shfl(u, jj);
            if (jj < m) {
                const uint4 v = *reinterpret_cast<const uint4*>(xb + (size_t)uu * 128 + 8 * l4);
                float f0, f1;
                unpack2(v.x, f0, f1); acc[0] += f0; acc[1] += f1;
                unpack2(v.y, f0, f1); acc[2] += f0; acc[3] += f1;
                unpack2(v.z, f0, f1); acc[4] += f0; acc[5] += f1;
                unpack2(v.w, f0, f1); acc[6] += f0; acc[7] += f1;
            }
        }
    }
    #pragma unroll
    for (int i = 0; i < 8; ++i) {
        acc[i] += __shfl_xor(acc[i], 16);
        acc[i] += __shfl_xor(acc[i], 32);
    }
    if (lane < 16) {
        float* op = out + (size_t)wid * 128 + 8 * lane;
        *reinterpret_cast<float4*>(op)     = make_float4(acc[0], acc[1], acc[2], acc[3]);
        *reinterpret_cast<float4*>(op + 4) = make_float4(acc[4], acc[5], acc[6], acc[7]);
    }
}

// out[r][:] = bf16( ns[r] * relu( nd[r] * (xin[r][:] @ W) + b ) ), W 128x128 row-major.
// X tile (32KB) in LDS; W streamed from L2. Wave w -> rows w*16..+15, lane -> cols lane,lane+64.
__global__ __launch_bounds__(256, 4) void mm128_kernel(const float* __restrict__ xin,
        const float* __restrict__ W, const float* __restrict__ bias,
        const float* __restrict__ norm_dst, const float* __restrict__ norm_src,
        ushort* __restrict__ out, int n) {
    __shared__ float Xl[64][128];
    int t = threadIdx.x;
    int row0 = blockIdx.x * 64;
    for (int i = t; i < 64 * 32; i += 256) {
        int r = i >> 5, k4 = i & 31;
        int gr = row0 + r;
        float4 xv = make_float4(0.f, 0.f, 0.f, 0.f);
        if (gr < n) xv = reinterpret_cast<const float4*>(xin)[(size_t)gr * 32 + k4];
        reinterpret_cast<float4*>(&Xl[r][0])[k4] = xv;
    }
    __syncthreads();
    int wv = t >> 6, lane = t & 63;
    int c0 = lane, c1 = lane + 64;
    float acc0[16], acc1[16];
    #pragma unroll
    for (int r = 0; r < 16; ++r) { acc0[r] = 0.f; acc1[r] = 0.f; }
    int rbase = wv * 16;
    const float* Wp0 = W + c0;
    const float* Wp1 = W + c1;
    for (int k = 0; k < 128; k += 4) {
        float w00 = Wp0[(k + 0) * 128], w10 = Wp1[(k + 0) * 128];
        float w01 = Wp0[(k + 1) * 128], w11 = Wp1[(k + 1) * 128];
        float w02 = Wp0[(k + 2) * 128], w12 = Wp1[(k + 2) * 128];
        float w03 = Wp0[(k + 3) * 128], w13 = Wp1[(k + 3) * 128];
        #pragma unroll
        for (int r = 0; r < 16; ++r) {
            float4 xv = *reinterpret_cast<const float4*>(&Xl[rbase + r][k]);
            acc0[r] = fmaf(xv.x, w00, acc0[r]);
            acc1[r] = fmaf(xv.x, w10, acc1[r]);
            acc0[r] = fmaf(xv.y, w01, acc0[r]);
            acc1[r] = fmaf(xv.y, w11, acc1[r]);
            acc0[r] = fmaf(xv.z, w02, acc0[r]);
            acc1[r] = fmaf(xv.z, w12, acc1[r]);
            acc0[r] = fmaf(xv.w, w03, acc0[r]);
            acc1[r] = fmaf(xv.w, w13, acc1[r]);
        }
    }
    float b0 = bias[c0], b1 = bias[c1];
    #pragma unroll
    for (int r = 0; r < 16; ++r) {
        int gr = row0 + rbase + r;
        if (gr < n) {
            float nd = norm_dst[gr], ns = norm_src[gr];
            float v0 = fmaxf(fmaf(nd, acc0[r], b0), 0.f) * ns;
            float v1 = fmaxf(fmaf(nd, acc1[r], b1), 0.f) * ns;
            out[(size_t)gr * 128 + c0] = f2bf(v0);
            out[(size_t)gr * 128 + c1] = f2bf(v1);
        }
    }
}

// y[r][c] = xin_bf16[r][:] @ W3[:,c], c < 40 (input already ns-prescaled). fp32 out.
__global__ __launch_bounds__(256, 4) void mm40_kernel(const ushort* __restrict__ xin,
        const float* __restrict__ W, float* __restrict__ out, int n) {
    __shared__ float Xl[64][128];
    int t = threadIdx.x;
    int row0 = blockIdx.x * 64;
    for (int i = t; i < 1024; i += 256) {
        int r = i >> 4, c8 = i & 15;
        int gr = row0 + r;
        float4 a0 = make_float4(0.f, 0.f, 0.f, 0.f);
        float4 a1 = make_float4(0.f, 0.f, 0.f, 0.f);
        if (gr < n) {
            uint4 v = *reinterpret_cast<const uint4*>(xin + (size_t)gr * 128 + 8 * c8);
            unpack2(v.x, a0.x, a0.y); unpack2(v.y, a0.z, a0.w);
            unpack2(v.z, a1.x, a1.y); unpack2(v.w, a1.z, a1.w);
        }
        float4* lp = reinterpret_cast<float4*>(&Xl[r][8 * c8]);
        lp[0] = a0; lp[1] = a1;
    }
    __syncthreads();
    int wv = t >> 6, lane = t & 63;
    int c = (lane < 40) ? lane : 0;
    float acc[16];
    #pragma unroll
    for (int r = 0; r < 16; ++r) acc[r] = 0.f;
    int rbase = wv * 16;
    const float* Wp = W + c;
    for (int k = 0; k < 128; k += 2) {
        float w0 = Wp[(k + 0) * 40];
        float w1 = Wp[(k + 1) * 40];
        #pragma unroll
        for (int r = 0; r < 16; ++r) {
            float2 xv = *reinterpret_cast<const float2*>(&Xl[rbase + r][k]);
            acc[r] = fmaf(xv.x, w0, acc[r]);
            acc[r] = fmaf(xv.y, w1, acc[r]);
        }
    }
    if (lane < 40) {
        #pragma unroll
        for (int r = 0; r < 16; ++r) {
            int gr = row0 + rbase + r;
            if (gr < n) out[(size_t)gr * 40 + lane] = acc[r];
        }
    }
}

// out[v][c] = norm_dst[v] * sum_{u->v} y[u][c] + b3[c], c < 40. One wave/node.
__global__ __launch_bounds__(256) void agg40_kernel(const float* __restrict__ y,
        const int* __restrict__ row_ptr, const int* __restrict__ col,
        const float* __restrict__ norm_dst, const float* __restrict__ b3,
        float* __restrict__ out, int n) {
    int wid  = (blockIdx.x * blockDim.x + threadIdx.x) >> 6;
    int lane = threadIdx.x & 63;
    if (wid >= n) return;
    int start = row_ptr[wid], end = row_ptr[wid + 1];
    float acc = 0.f;
    for (int b = start; b < end; b += 64) {
        int m = end - b; if (m > 64) m = 64;
        int u = 0;
        if (lane < m) u = col[b + lane];
        for (int j = 0; j < m; ++j) {
            int uu = __shfl(u, j);
            if (lane < 40) acc += y[(size_t)uu * 40 + lane];
        }
    }
    if (lane < 40) out[(size_t)wid * 40 + lane] = norm_dst[wid] * acc + b3[lane];
}

extern "C" void kernel_launch(void* const* d_in, const int* in_sizes, int n_in,
                              void* d_out, int out_size, void* d_ws, size_t ws_size,
                              hipStream_t stream) {
    const float* features = (const float*)d_in[0];
    const int*   ei       = (const int*)d_in[1];
    const float* W1 = (const float*)d_in[2];
    const float* b1 = (const float*)d_in[3];
    const float* W2 = (const float*)d_in[4];
    const float* b2 = (const float*)d_in[5];
    const float* W3 = (const float*)d_in[6];
    const float* b3 = (const float*)d_in[7];

    const int n = in_sizes[0] / 128;
    const int E = in_sizes[1] / 2;

    char* w = (char*)d_ws;
    auto alloc = [&](size_t bytes) {
        char* p = w;
        w += (bytes + 255) & ~(size_t)255;
        return p;
    };
    int*    deg      = (int*)   alloc((size_t)2 * n * 4);  // cnt_src | cnt_dst
    float*  norm_src = (float*) alloc((size_t)n * 4);
    float*  norm_dst = (float*) alloc((size_t)n * 4);
    int*    row_ptr  = (int*)   alloc((size_t)(n + 1) * 4);
    int*    partials = (int*)   alloc((size_t)256 * 4);
    int*    tmp_slot = (int*)   alloc((size_t)E * 4);
    int*    col      = (int*)   alloc((size_t)E * 4);
    ushort* xb       = (ushort*)alloc((size_t)n * 128 * 2);  // bf16 node table (reused per layer)
    float*  bufA     = (float*) alloc((size_t)n * 128 * 4);  // fp32 agg / y buffer

    int* deg_out = deg;      // cnt_src
    int* deg_in  = deg + n;  // cnt_dst

    hipMemsetAsync(deg, 0, (size_t)2 * n * 4, stream);

    int e4b = (E / 4 + 255) / 256;  // 4 edges per thread
    int sb  = (n + SCAN_CHUNK - 1) / SCAN_CHUNK;
    int cb  = (n * 32 + 255) / 256;

    count_slot_kernel<<<e4b, 256, 0, stream>>>(ei, E, deg_out, deg_in, tmp_slot);
    scan_blocksum<<<sb, 256, 0, stream>>>(deg_in, n, partials);
    scan_partials<<<1, 256, 0, stream>>>(partials, sb, row_ptr, n);
    scan_emit<<<sb, 256, 0, stream>>>(deg_in, deg_out, partials, n,
                                      row_ptr, norm_src, norm_dst);
    scatter_kernel<<<e4b, 256, 0, stream>>>(ei, E, row_ptr, tmp_slot, col);
    convert_kernel<<<cb, 256, 0, stream>>>(features, norm_src, xb, n);

    int ab = (n + 3) / 4;
    int mb = (n + 63) / 64;

    agg128_kernel<<<ab, 256, 0, stream>>>(xb, row_ptr, col, bufA, n);
    mm128_kernel<<<mb, 256, 0, stream>>>(bufA, W1, b1, norm_dst, norm_src, xb, n);
    agg128_kernel<<<ab, 256, 0, stream>>>(xb, row_ptr, col, bufA, n);
    mm128_kernel<<<mb, 256, 0, stream>>>(bufA, W2, b2, norm_dst, norm_src, xb, n);
    mm40_kernel<<<mb, 256, 0, stream>>>(xb, W3, bufA, n);
    agg40_kernel<<<ab, 256, 0, stream>>>(bufA, row_ptr, col, norm_dst, b3, (float*)d_out, n);
}

// Round 6
// 333.048 us; speedup vs baseline: 1.8697x; 1.0234x over previous
//
#include <hip/hip_runtime.h>

// GCN 3-layer forward on MI355X.
// CSR build (by dst): combined count+slot atomic pass (1 edge/thread),
// hierarchical scan, fused atomic-free scatter + bf16 convert.
// Per layer:
//   xb[u] = bf16(norm_src[u] * x[u])          (pre-scaled bf16 node table)
//   agg[v] = sum_{u->v} xb[u]                 (pure bf16 gather-sum, fp32 accum)
//   h' = bf16( ns * relu(nd * agg @ W + b) )  (next layer's pre-scaled table)
// Layer 3: y = h2' @ W3 (fp32), then 40-dim agg with nd + b3.

#define SCAN_CHUNK 4096

__device__ __forceinline__ ushort f2bf(float f) {
    unsigned u = __float_as_uint(f);
    unsigned r = (u + 0x7fffu + ((u >> 16) & 1u)) >> 16;  // RN-even
    return (ushort)r;
}
__device__ __forceinline__ void unpack2(unsigned w, float& lo, float& hi) {
    lo = __uint_as_float(w << 16);
    hi = __uint_as_float(w & 0xffff0000u);
}

// Combined histogram + slot assignment: 2 atomic ops per edge (1 returning).
// 1 edge/thread: maximize waves in flight to hide atomic latency.
__global__ __launch_bounds__(256) void count_slot_kernel(const int* __restrict__ ei, int E,
        int* __restrict__ cnt_src, int* __restrict__ cnt_dst, int* __restrict__ tmp_slot) {
    int e = blockIdx.x * 256 + threadIdx.x;
    if (e < E) {
        int s = ei[e];
        int d = ei[E + e];
        atomicAdd(&cnt_src[s], 1);
        tmp_slot[e] = atomicAdd(&cnt_dst[d], 1);
    }
}

__global__ __launch_bounds__(256) void scan_blocksum(const int* __restrict__ deg_in, int n,
                                                     int* __restrict__ partials) {
    __shared__ int red[256];
    int t = threadIdx.x;
    int base = blockIdx.x * SCAN_CHUNK;
    int s = 0;
    for (int i = t; i < SCAN_CHUNK; i += 256) {
        int idx = base + i;
        if (idx < n) s += deg_in[idx];
    }
    red[t] = s;
    __syncthreads();
    for (int off = 128; off > 0; off >>= 1) {
        if (t < off) red[t] += red[t + off];
        __syncthreads();
    }
    if (t == 0) partials[blockIdx.x] = red[0];
}

__global__ __launch_bounds__(256) void scan_partials(int* __restrict__ partials, int nparts,
                                                     int* __restrict__ row_ptr, int n) {
    __shared__ int s[256];
    int t = threadIdx.x;
    s[t] = (t < nparts) ? partials[t] : 0;
    __syncthreads();
    for (int off = 1; off < 256; off <<= 1) {
        int v = (t >= off) ? s[t - off] : 0;
        __syncthreads();
        s[t] += v;
        __syncthreads();
    }
    int incl = s[t];
    int excl = incl - ((t < nparts) ? partials[t] : 0);
    if (t < nparts) partials[t] = excl;
    if (t == 255) row_ptr[n] = incl;
}

// Per-chunk exclusive scan -> row_ptr, fused norm compute.
__global__ __launch_bounds__(256) void scan_emit(const int* __restrict__ deg_in,
                                                 const int* __restrict__ deg_out,
                                                 const int* __restrict__ partials, int n,
                                                 int* __restrict__ row_ptr,
                                                 float* __restrict__ norm_src,
                                                 float* __restrict__ norm_dst) {
    __shared__ int tsum[256];
    int t = threadIdx.x;
    int base = blockIdx.x * SCAN_CHUNK + t * 16;
    int local[16];
    int s = 0;
    #pragma unroll
    for (int i = 0; i < 16; ++i) {
        int idx = base + i;
        int v = (idx < n) ? deg_in[idx] : 0;
        local[i] = v;
        s += v;
    }
    tsum[t] = s;
    __syncthreads();
    for (int off = 1; off < 256; off <<= 1) {
        int v = (t >= off) ? tsum[t - off] : 0;
        __syncthreads();
        tsum[t] += v;
        __syncthreads();
    }
    int run = partials[blockIdx.x] + (t ? tsum[t - 1] : 0);
    #pragma unroll
    for (int i = 0; i < 16; ++i) {
        int idx = base + i;
        if (idx < n) {
            row_ptr[idx] = run;
            run += local[i];
            int di = local[i] > 0 ? local[i] : 1;
            int dq = deg_out[idx] > 0 ? deg_out[idx] : 1;
            norm_dst[idx] = rsqrtf((float)di);
            norm_src[idx] = rsqrtf((float)dq);
        }
    }
}

// Fused heterogeneous dispatch: blocks [0, eb) scatter CSR cols (atomic-free),
// blocks [eb, eb+cb) convert features to pre-scaled bf16. Independent work;
// overlapping hides the random-write latency under streaming converts.
__global__ __launch_bounds__(256) void scatter_convert_kernel(const int* __restrict__ ei, int E,
        const int* __restrict__ row_ptr, const int* __restrict__ tmp_slot,
        int* __restrict__ col, int eb,
        const float* __restrict__ x, const float* __restrict__ ns,
        ushort* __restrict__ xb, int n) {
    if ((int)blockIdx.x < eb) {
        int e = blockIdx.x * 256 + threadIdx.x;
        if (e < E) {
            int s = ei[e];
            int d = ei[E + e];
            col[row_ptr[d] + tmp_slot[e]] = s;
        }
    } else {
        int i = (blockIdx.x - eb) * 256 + threadIdx.x;
        if (i < n * 32) {
            int row = i >> 5;
            float s = ns[row];
            float4 v = reinterpret_cast<const float4*>(x)[i];
            ushort4 o;
            o.x = f2bf(v.x * s); o.y = f2bf(v.y * s);
            o.z = f2bf(v.z * s); o.w = f2bf(v.w * s);
            reinterpret_cast<ushort4*>(xb)[i] = o;
        }
    }
}

// One wave per node: out[v][:] = sum_{u->v} xb[u][:] (bf16 rows, fp32 accum).
// 4 edges per iteration: 16 lanes x 8 dims each (16B loads); quarter-wave combine at end.
__global__ __launch_bounds__(256) void agg128_kernel(const ushort* __restrict__ xb,
        const int* __restrict__ row_ptr, const int* __restrict__ col,
        float* __restrict__ out, int n) {
    int wid  = (blockIdx.x * blockDim.x + threadIdx.x) >> 6;
    int lane = threadIdx.x & 63;
    if (wid >= n) return;
    int start = row_ptr[wid], end = row_ptr[wid + 1];
    int quarter = lane >> 4, l4 = lane & 15;
    float acc[8];
    #pragma unroll
    for (int i = 0; i < 8; ++i) acc[i] = 0.f;
    for (int b = start; b < end; b += 64) {
        int m = end - b; if (m > 64) m = 64;
        int u = 0;
        if (lane < m) u = col[b + lane];
        for (int j = 0; j < m; j += 4) {
            int jj = j + quarter;
            int uu = __shfl(u, jj);
            if (jj < m) {
                const uint4 v = *reinterpret_cast<const uint4*>(xb + (size_t)uu * 128 + 8 * l4);
                float f0, f1;
                unpack2(v.x, f0, f1); acc[0] += f0; acc[1] += f1;
                unpack2(v.y, f0, f1); acc[2] += f0; acc[3] += f1;
                unpack2(v.z, f0, f1); acc[4] += f0; acc[5] += f1;
                unpack2(v.w, f0, f1); acc[6] += f0; acc[7] += f1;
            }
        }
    }
    #pragma unroll
    for (int i = 0; i < 8; ++i) {
        acc[i] += __shfl_xor(acc[i], 16);
        acc[i] += __shfl_xor(acc[i], 32);
    }
    if (lane < 16) {
        float* op = out + (size_t)wid * 128 + 8 * lane;
        *reinterpret_cast<float4*>(op)     = make_float4(acc[0], acc[1], acc[2], acc[3]);
        *reinterpret_cast<float4*>(op + 4) = make_float4(acc[4], acc[5], acc[6], acc[7]);
    }
}

// out[r][:] = bf16( ns[r] * relu( nd[r] * (xin[r][:] @ W) + b ) ), W 128x128 row-major.
// 32 rows/block (16KB LDS) for block-level parallelism; W streamed from L2.
// Wave w -> rows w*8..+7, lane -> cols lane, lane+64.
__global__ __launch_bounds__(256, 4) void mm128_kernel(const float* __restrict__ xin,
        const float* __restrict__ W, const float* __restrict__ bias,
        const float* __restrict__ norm_dst, const float* __restrict__ norm_src,
        ushort* __restrict__ out, int n) {
    __shared__ float Xl[32][128];
    int t = threadIdx.x;
    int row0 = blockIdx.x * 32;
    for (int i = t; i < 32 * 32; i += 256) {
        int r = i >> 5, k4 = i & 31;
        int gr = row0 + r;
        float4 xv = make_float4(0.f, 0.f, 0.f, 0.f);
        if (gr < n) xv = reinterpret_cast<const float4*>(xin)[(size_t)gr * 32 + k4];
        reinterpret_cast<float4*>(&Xl[r][0])[k4] = xv;
    }
    __syncthreads();
    int wv = t >> 6, lane = t & 63;
    int c0 = lane, c1 = lane + 64;
    float acc0[8], acc1[8];
    #pragma unroll
    for (int r = 0; r < 8; ++r) { acc0[r] = 0.f; acc1[r] = 0.f; }
    int rbase = wv * 8;
    const float* Wp0 = W + c0;
    const float* Wp1 = W + c1;
    for (int k = 0; k < 128; k += 4) {
        float w00 = Wp0[(k + 0) * 128], w10 = Wp1[(k + 0) * 128];
        float w01 = Wp0[(k + 1) * 128], w11 = Wp1[(k + 1) * 128];
        float w02 = Wp0[(k + 2) * 128], w12 = Wp1[(k + 2) * 128];
        float w03 = Wp0[(k + 3) * 128], w13 = Wp1[(k + 3) * 128];
        #pragma unroll
        for (int r = 0; r < 8; ++r) {
            float4 xv = *reinterpret_cast<const float4*>(&Xl[rbase + r][k]);
            acc0[r] = fmaf(xv.x, w00, acc0[r]);
            acc1[r] = fmaf(xv.x, w10, acc1[r]);
            acc0[r] = fmaf(xv.y, w01, acc0[r]);
            acc1[r] = fmaf(xv.y, w11, acc1[r]);
            acc0[r] = fmaf(xv.z, w02, acc0[r]);
            acc1[r] = fmaf(xv.z, w12, acc1[r]);
            acc0[r] = fmaf(xv.w, w03, acc0[r]);
            acc1[r] = fmaf(xv.w, w13, acc1[r]);
        }
    }
    float b0 = bias[c0], b1 = bias[c1];
    #pragma unroll
    for (int r = 0; r < 8; ++r) {
        int gr = row0 + rbase + r;
        if (gr < n) {
            float nd = norm_dst[gr], ns = norm_src[gr];
            float v0 = fmaxf(fmaf(nd, acc0[r], b0), 0.f) * ns;
            float v1 = fmaxf(fmaf(nd, acc1[r], b1), 0.f) * ns;
            out[(size_t)gr * 128 + c0] = f2bf(v0);
            out[(size_t)gr * 128 + c1] = f2bf(v1);
        }
    }
}

// y[r][c] = xin_bf16[r][:] @ W3[:,c], c < 40 (input already ns-prescaled). fp32 out.
// 32 rows/block.
__global__ __launch_bounds__(256, 4) void mm40_kernel(const ushort* __restrict__ xin,
        const float* __restrict__ W, float* __restrict__ out, int n) {
    __shared__ float Xl[32][128];
    int t = threadIdx.x;
    int row0 = blockIdx.x * 32;
    for (int i = t; i < 512; i += 256) {
        int r = i >> 4, c8 = i & 15;
        int gr = row0 + r;
        float4 a0 = make_float4(0.f, 0.f, 0.f, 0.f);
        float4 a1 = make_float4(0.f, 0.f, 0.f, 0.f);
        if (gr < n) {
            uint4 v = *reinterpret_cast<const uint4*>(xin + (size_t)gr * 128 + 8 * c8);
            unpack2(v.x, a0.x, a0.y); unpack2(v.y, a0.z, a0.w);
            unpack2(v.z, a1.x, a1.y); unpack2(v.w, a1.z, a1.w);
        }
        float4* lp = reinterpret_cast<float4*>(&Xl[r][8 * c8]);
        lp[0] = a0; lp[1] = a1;
    }
    __syncthreads();
    int wv = t >> 6, lane = t & 63;
    int c = (lane < 40) ? lane : 0;
    float acc[8];
    #pragma unroll
    for (int r = 0; r < 8; ++r) acc[r] = 0.f;
    int rbase = wv * 8;
    const float* Wp = W + c;
    for (int k = 0; k < 128; k += 2) {
        float w0 = Wp[(k + 0) * 40];
        float w1 = Wp[(k + 1) * 40];
        #pragma unroll
        for (int r = 0; r < 8; ++r) {
            float2 xv = *reinterpret_cast<const float2*>(&Xl[rbase + r][k]);
            acc[r] = fmaf(xv.x, w0, acc[r]);
            acc[r] = fmaf(xv.y, w1, acc[r]);
        }
    }
    if (lane < 40) {
        #pragma unroll
        for (int r = 0; r < 8; ++r) {
            int gr = row0 + rbase + r;
            if (gr < n) out[(size_t)gr * 40 + lane] = acc[r];
        }
    }
}

// out[v][c] = norm_dst[v] * sum_{u->v} y[u][c] + b3[c], c < 40. One wave/node.
__global__ __launch_bounds__(256) void agg40_kernel(const float* __restrict__ y,
        const int* __restrict__ row_ptr, const int* __restrict__ col,
        const float* __restrict__ norm_dst, const float* __restrict__ b3,
        float* __restrict__ out, int n) {
    int wid  = (blockIdx.x * blockDim.x + threadIdx.x) >> 6;
    int lane = threadIdx.x & 63;
    if (wid >= n) return;
    int start = row_ptr[wid], end = row_ptr[wid + 1];
    float acc = 0.f;
    for (int b = start; b < end; b += 64) {
        int m = end - b; if (m > 64) m = 64;
        int u = 0;
        if (lane < m) u = col[b + lane];
        for (int j = 0; j < m; ++j) {
            int uu = __shfl(u, j);
            if (lane < 40) acc += y[(size_t)uu * 40 + lane];
        }
    }
    if (lane < 40) out[(size_t)wid * 40 + lane] = norm_dst[wid] * acc + b3[lane];
}

extern "C" void kernel_launch(void* const* d_in, const int* in_sizes, int n_in,
                              void* d_out, int out_size, void* d_ws, size_t ws_size,
                              hipStream_t stream) {
    const float* features = (const float*)d_in[0];
    const int*   ei       = (const int*)d_in[1];
    const float* W1 = (const float*)d_in[2];
    const float* b1 = (const float*)d_in[3];
    const float* W2 = (const float*)d_in[4];
    const float* b2 = (const float*)d_in[5];
    const float* W3 = (const float*)d_in[6];
    const float* b3 = (const float*)d_in[7];

    const int n = in_sizes[0] / 128;
    const int E = in_sizes[1] / 2;

    char* w = (char*)d_ws;
    auto alloc = [&](size_t bytes) {
        char* p = w;
        w += (bytes + 255) & ~(size_t)255;
        return p;
    };
    int*    deg      = (int*)   alloc((size_t)2 * n * 4);  // cnt_src | cnt_dst
    float*  norm_src = (float*) alloc((size_t)n * 4);
    float*  norm_dst = (float*) alloc((size_t)n * 4);
    int*    row_ptr  = (int*)   alloc((size_t)(n + 1) * 4);
    int*    partials = (int*)   alloc((size_t)256 * 4);
    int*    tmp_slot = (int*)   alloc((size_t)E * 4);
    int*    col      = (int*)   alloc((size_t)E * 4);
    ushort* xb       = (ushort*)alloc((size_t)n * 128 * 2);  // bf16 node table (reused per layer)
    float*  bufA     = (float*) alloc((size_t)n * 128 * 4);  // fp32 agg / y buffer

    int* deg_out = deg;      // cnt_src
    int* deg_in  = deg + n;  // cnt_dst

    hipMemsetAsync(deg, 0, (size_t)2 * n * 4, stream);

    int eb = (E + 255) / 256;            // 1 edge per thread
    int sb = (n + SCAN_CHUNK - 1) / SCAN_CHUNK;
    int cb = (n * 32 + 255) / 256;       // convert blocks

    count_slot_kernel<<<eb, 256, 0, stream>>>(ei, E, deg_out, deg_in, tmp_slot);
    scan_blocksum<<<sb, 256, 0, stream>>>(deg_in, n, partials);
    scan_partials<<<1, 256, 0, stream>>>(partials, sb, row_ptr, n);
    scan_emit<<<sb, 256, 0, stream>>>(deg_in, deg_out, partials, n,
                                      row_ptr, norm_src, norm_dst);
    scatter_convert_kernel<<<eb + cb, 256, 0, stream>>>(ei, E, row_ptr, tmp_slot, col, eb,
                                                        features, norm_src, xb, n);

    int ab = (n + 3) / 4;
    int mb = (n + 31) / 32;

    agg128_kernel<<<ab, 256, 0, stream>>>(xb, row_ptr, col, bufA, n);
    mm128_kernel<<<mb, 256, 0, stream>>>(bufA, W1, b1, norm_dst, norm_src, xb, n);
    agg128_kernel<<<ab, 256, 0, stream>>>(xb, row_ptr, col, bufA, n);
    mm128_kernel<<<mb, 256, 0, stream>>>(bufA, W2, b2, norm_dst, norm_src, xb, n);
    mm40_kernel<<<mb, 256, 0, stream>>>(xb, W3, bufA, n);
    agg40_kernel<<<ab, 256, 0, stream>>>(bufA, row_ptr, col, norm_dst, b3, (float*)d_out, n);
}